// Round 4
// baseline (273.226 us; speedup 1.0000x reference)
//
#include <hip/hip_runtime.h>
#include <hip/hip_bf16.h>

// Problem constants
#define B 32
#define T 2048
#define E 512
#define D 1024
#define H 128

typedef __attribute__((ext_vector_type(8))) short bf16x8;  // MFMA A/B frag (4 VGPRs)
typedef __attribute__((ext_vector_type(4))) float f32x4;   // MFMA C/D frag

static __device__ __forceinline__ short f2b(float f) {
  __hip_bfloat16 h = __float2bfloat16(f);  // HW RNE cvt (compiler pairs into cvt_pk)
  return __builtin_bit_cast(short, h);
}

// ---------------------------------------------------------------------------
// Kernel 1 (fused prep):
//  blocks 0..31  : dec[b][h] = b_enc[h] + sum_k ds[b][k] * Wd[k][h]
//  blocks 32..47 : WeT[c][h][s^(h&7)][j] = bf16(We[(c*64+s*8+j)*H + h])
//    (pre-swizzled transposed W_enc so linear global_load_lds staging lands a
//     bank-conflict-mitigated LDS layout for ds_read_b128 B-frags)
// ---------------------------------------------------------------------------
__global__ __launch_bounds__(512) void prep_kernel(
    const float* __restrict__ ds, const float* __restrict__ Wd,
    const float* __restrict__ be, const float* __restrict__ We,
    float* __restrict__ dec_ws, char* __restrict__ WeT) {
  const int tid = threadIdx.x;
  if (blockIdx.x < 32) {
    const int b = blockIdx.x;
    const int h = tid & 127;
    const int kg = tid >> 7;  // 0..3, each covers 256 k
    __shared__ float sds[D];
    __shared__ float sred[4][H];
    for (int i = tid; i < D; i += 512) sds[i] = ds[b * D + i];
    __syncthreads();
    float acc = 0.0f;
    const int k0 = kg * 256;
#pragma unroll 8
    for (int k = k0; k < k0 + 256; ++k) acc = fmaf(sds[k], Wd[k * H + h], acc);
    sred[kg][h] = acc;
    __syncthreads();
    if (kg == 0)
      dec_ws[b * H + h] = be[h] + sred[0][h] + sred[1][h] + sred[2][h] + sred[3][h];
  } else {
    const int id = (blockIdx.x - 32) * 512 + tid;  // 0..8191
    const int c = id >> 10;                        // k-chunk 0..7
    const int rem = id & 1023;
    const int h = rem & 127;                       // coalesced over h
    const int s = rem >> 7;                        // slot 0..7
    const int k0 = c * 64 + s * 8;
    bf16x8 v;
#pragma unroll
    for (int j = 0; j < 8; ++j) v[j] = f2b(We[(k0 + j) * H + h]);
    *(bf16x8*)(WeT + c * 16384 + h * 128 + ((s ^ (h & 7)) * 16)) = v;
  }
}

// ---------------------------------------------------------------------------
// Kernel 2: erg via bf16 MFMA, whole-WeT-in-LDS, barrier-free K-loop.
// 1024 thr = 16 waves, 1 block/CU (128 KiB LDS), 256 rows/block, grid = 256.
// ---------------------------------------------------------------------------
__global__ __launch_bounds__(1024, 1) void erg_mfma_kernel(
    const float* __restrict__ enc, const char* __restrict__ WeT,
    const float* __restrict__ dec_ws, const float* __restrict__ ww,
    const float* __restrict__ wb, float* __restrict__ erg_ws) {
  __shared__ __align__(16) char smem[131072];
  const int tid = threadIdx.x;
  const int lane = tid & 63;
  const int w = tid >> 6;    // wave 0..15
  const int m = lane & 15;   // A-row / D-col lane index
  const int g = lane >> 4;   // k-subgroup 0..3
  const int row0 = blockIdx.x * 256 + w * 16;  // wave's 16 rows in [0, B*T)
  const int b = row0 >> 11;                    // T = 2048 rows per b

  // Stage entire WeT (128 KiB) linearly: thread tid covers 8 x 16B.
#pragma unroll
  for (int j = 0; j < 8; ++j)
    __builtin_amdgcn_global_load_lds(
        (const __attribute__((address_space(1))) void*)(WeT + j * 16384 + tid * 16),
        (__attribute__((address_space(3))) void*)(&smem[j * 16384 + tid * 16]),
        16, 0, 0);

  // acc init with dec (includes b_enc): D col = n*16 + m; 4 row-regs identical
  f32x4 acc[8];
#pragma unroll
  for (int n = 0; n < 8; ++n) {
    const float d = dec_ws[b * H + n * 16 + m];
    acc[n] = (f32x4){d, d, d, d};
  }

  // lane's A pointer: row (row0+m), k-offset g*8
  const float* arow = enc + (size_t)(row0 + m) * E + g * 8;

  // preload A for chunk 0
  float4 a0 = *(const float4*)(arow);
  float4 a1 = *(const float4*)(arow + 4);
  float4 a2 = *(const float4*)(arow + 32);
  float4 a3 = *(const float4*)(arow + 36);

  asm volatile("s_waitcnt vmcnt(0)" ::: "memory");
  __syncthreads();

#pragma unroll
  for (int c = 0; c < 8; ++c) {
    float4 n0, n1, n2, n3;
    if (c < 7) {  // software-pipelined next-chunk A loads (no barriers -> overlap)
      const float* ak = arow + (c + 1) * 64;
      n0 = *(const float4*)(ak);
      n1 = *(const float4*)(ak + 4);
      n2 = *(const float4*)(ak + 32);
      n3 = *(const float4*)(ak + 36);
    }
    bf16x8 af0, af1;
    af0[0] = f2b(a0.x); af0[1] = f2b(a0.y); af0[2] = f2b(a0.z); af0[3] = f2b(a0.w);
    af0[4] = f2b(a1.x); af0[5] = f2b(a1.y); af0[6] = f2b(a1.z); af0[7] = f2b(a1.w);
    af1[0] = f2b(a2.x); af1[1] = f2b(a2.y); af1[2] = f2b(a2.z); af1[3] = f2b(a2.w);
    af1[4] = f2b(a3.x); af1[5] = f2b(a3.y); af1[6] = f2b(a3.z); af1[7] = f2b(a3.w);

#pragma unroll
    for (int kk = 0; kk < 2; ++kk) {
      const int slot = (((kk * 4) + g) ^ (m & 7)) * 16;
      const bf16x8 af = kk ? af1 : af0;
#pragma unroll
      for (int n = 0; n < 8; ++n) {
        const bf16x8 bf =
            *(const bf16x8*)(&smem[c * 16384 + (n * 16 + m) * 128 + slot]);
        acc[n] = __builtin_amdgcn_mfma_f32_16x16x32_bf16(af, bf, acc[n], 0, 0, 0);
      }
    }
    a0 = n0; a1 = n1; a2 = n2; a3 = n3;
  }

  // Epilogue: erg[row] = wb + sum_h ww[h]*tanh(acc). D: row=g*4+j, col=n*16+m.
  const float wbv = wb[0];
  float wwreg[8];
#pragma unroll
  for (int n = 0; n < 8; ++n) wwreg[n] = ww[n * 16 + m];
#pragma unroll
  for (int j = 0; j < 4; ++j) {
    float gsum = 0.0f;
#pragma unroll
    for (int n = 0; n < 8; ++n) {
      const float x = acc[n][j];
      const float th = 1.0f - 2.0f / (__expf(2.0f * x) + 1.0f);
      gsum = fmaf(wwreg[n], th, gsum);
    }
#pragma unroll
    for (int off = 1; off < 16; off <<= 1) gsum += __shfl_xor(gsum, off, 64);
    if (m == 0) erg_ws[row0 + g * 4 + j] = gsum + wbv;
  }
}

// ---------------------------------------------------------------------------
// Kernel 3 (fused): masked softmax over t + attention context, one block per b.
// 1024 thr = 16 waves. Phase A: load erg row (2 elems/thread), block-reduce
// max and sum, write weights to w_out AND LDS. Phase B: 8 t-groups x 128
// threads stream enc rows (L3-resident after erg pass), accumulate float4,
// LDS-reduce 8 partials, write ctx.
// ---------------------------------------------------------------------------
__global__ __launch_bounds__(1024, 1) void softmax_ctx_kernel(
    const float* __restrict__ enc, const float* __restrict__ erg_ws,
    const int* __restrict__ src_lens, float* __restrict__ w_out,
    float* __restrict__ ctx) {
  const int b = blockIdx.x;
  const int tid = threadIdx.x;
  const int lane = tid & 63, w = tid >> 6;
  const int n = src_lens[b];

  __shared__ float sw[T];        // weights, 8 KB
  __shared__ float red8[8][E];   // ctx partials, 16 KB
  __shared__ float sred[16];
  __shared__ float sscal[2];

  // ---- softmax ----
  const float x0 = erg_ws[b * T + tid];
  const float x1 = erg_ws[b * T + tid + 1024];
  const float v0 = (tid < n) ? x0 : -1e30f;
  const float v1 = (tid + 1024 < n) ? x1 : -1e30f;

  float mx = fmaxf(v0, v1);
#pragma unroll
  for (int off = 32; off > 0; off >>= 1) mx = fmaxf(mx, __shfl_xor(mx, off, 64));
  if (lane == 0) sred[w] = mx;
  __syncthreads();
  if (tid == 0) {
    float m2 = sred[0];
#pragma unroll
    for (int i = 1; i < 16; ++i) m2 = fmaxf(m2, sred[i]);
    sscal[0] = m2;
  }
  __syncthreads();
  mx = sscal[0];

  const float e0 = (v0 > -1e29f) ? __expf(v0 - mx) : 0.0f;
  const float e1 = (v1 > -1e29f) ? __expf(v1 - mx) : 0.0f;
  float s = e0 + e1;
#pragma unroll
  for (int off = 32; off > 0; off >>= 1) s += __shfl_xor(s, off, 64);
  if (lane == 0) sred[w] = s;
  __syncthreads();
  if (tid == 0) {
    float ss = 0.0f;
#pragma unroll
    for (int i = 0; i < 16; ++i) ss += sred[i];
    sscal[1] = 1.0f / ss;
  }
  __syncthreads();
  const float inv = sscal[1];

  const float w0 = e0 * inv, w1 = e1 * inv;
  w_out[b * T + tid] = w0;
  w_out[b * T + tid + 1024] = w1;
  sw[tid] = w0;
  sw[tid + 1024] = w1;
  __syncthreads();

  // ---- context ----
  const int e4 = tid & 127;   // float4 column
  const int tg = tid >> 7;    // 0..7 t-group (256 consecutive t each)
  const float4* ep = (const float4*)(enc + ((size_t)b * T + tg * 256) * E) + e4;
  const float* swp = &sw[tg * 256];
  float4 acc = {0.0f, 0.0f, 0.0f, 0.0f};
#pragma unroll 8
  for (int i = 0; i < 256; ++i) {
    const float4 e = ep[(size_t)i * (E / 4)];
    const float wv = swp[i];
    acc.x = fmaf(e.x, wv, acc.x);
    acc.y = fmaf(e.y, wv, acc.y);
    acc.z = fmaf(e.z, wv, acc.z);
    acc.w = fmaf(e.w, wv, acc.w);
  }
  *(float4*)&red8[tg][e4 * 4] = acc;
  __syncthreads();
  if (tid < E) {
    float r = 0.0f;
#pragma unroll
    for (int p = 0; p < 8; ++p) r += red8[p][tid];
    ctx[b * E + tid] = r;
  }
}

// ---------------------------------------------------------------------------
extern "C" void kernel_launch(void* const* d_in, const int* in_sizes, int n_in,
                              void* d_out, int out_size, void* d_ws,
                              size_t ws_size, hipStream_t stream) {
  const float* enc = (const float*)d_in[0];   // [B,T,E]
  const int* src_lens = (const int*)d_in[1];  // [B]
  const float* ds = (const float*)d_in[2];    // [B,D]
  // d_in[3] = mask (bool) -- recomputed from src_lens
  const float* We = (const float*)d_in[4];    // [E,H]
  const float* be = (const float*)d_in[5];    // [H]
  const float* Wd = (const float*)d_in[6];    // [D,H]
  const float* ww = (const float*)d_in[7];    // [H,1]
  const float* wb = (const float*)d_in[8];    // [1]

  float* ctx_out = (float*)d_out;             // [B,E]
  float* w_out = (float*)d_out + B * E;       // [B,T]

  float* ws = (float*)d_ws;
  float* dec_ws = ws;                          // 4096 f
  float* erg_ws = ws + B * H;                  // 65536 f
  char* WeT = (char*)(ws + B * H + B * T);     // 128 KiB (bf16, pre-swizzled)

  prep_kernel<<<48, 512, 0, stream>>>(ds, Wd, be, We, dec_ws, WeT);
  erg_mfma_kernel<<<(B * T) / 256, 1024, 0, stream>>>(enc, WeT, dec_ws, ww, wb, erg_ws);
  softmax_ctx_kernel<<<B, 1024, 0, stream>>>(enc, erg_ws, src_lens, w_out, ctx_out);
}

// Round 6
// 249.895 us; speedup vs baseline: 1.0934x; 1.0934x over previous
//
#include <hip/hip_runtime.h>
#include <hip/hip_bf16.h>

// Problem constants
#define B 32
#define T 2048
#define E 512
#define D 1024
#define H 128

typedef __attribute__((ext_vector_type(8))) short bf16x8;  // MFMA A/B frag (4 VGPRs)
typedef __attribute__((ext_vector_type(4))) float f32x4;   // MFMA C/D frag

static __device__ __forceinline__ short f2b(float f) {
  __hip_bfloat16 h = __float2bfloat16(f);  // HW RNE cvt (compiler pairs into cvt_pk)
  return __builtin_bit_cast(short, h);
}

// ---------------------------------------------------------------------------
// Kernel 1 (fused prep):
//  blocks 0..31  : dec[b][h] = b_enc[h] + sum_k ds[b][k] * Wd[k][h]
//  blocks 32..47 : WeT[c][h][s^(h&7)][j] = bf16(We[(c*64+s*8+j)*H + h])
//                  + zero ctx (atomicAdd destination; d_out poisoned 0xAA)
// ---------------------------------------------------------------------------
__global__ __launch_bounds__(512) void prep_kernel(
    const float* __restrict__ ds, const float* __restrict__ Wd,
    const float* __restrict__ be, const float* __restrict__ We,
    float* __restrict__ dec_ws, char* __restrict__ WeT,
    float* __restrict__ ctx) {
  const int tid = threadIdx.x;
  if (blockIdx.x < 32) {
    const int b = blockIdx.x;
    const int h = tid & 127;
    const int kg = tid >> 7;  // 0..3, each covers 256 k
    __shared__ float sds[D];
    __shared__ float sred[4][H];
    for (int i = tid; i < D; i += 512) sds[i] = ds[b * D + i];
    __syncthreads();
    float acc = 0.0f;
    const int k0 = kg * 256;
#pragma unroll 8
    for (int k = k0; k < k0 + 256; ++k) acc = fmaf(sds[k], Wd[k * H + h], acc);
    sred[kg][h] = acc;
    __syncthreads();
    if (kg == 0)
      dec_ws[b * H + h] = be[h] + sred[0][h] + sred[1][h] + sred[2][h] + sred[3][h];
  } else {
    const int id = (blockIdx.x - 32) * 512 + tid;  // 0..8191
    // zero ctx: 16384 floats over 8192 threads
    ctx[id * 2] = 0.0f;
    ctx[id * 2 + 1] = 0.0f;
    const int c = id >> 10;                        // k-chunk 0..7
    const int rem = id & 1023;
    const int h = rem & 127;                       // coalesced over h
    const int s = rem >> 7;                        // slot 0..7
    const int k0 = c * 64 + s * 8;
    bf16x8 v;
#pragma unroll
    for (int j = 0; j < 8; ++j) v[j] = f2b(We[(k0 + j) * H + h]);
    *(bf16x8*)(WeT + c * 16384 + h * 128 + ((s ^ (h & 7)) * 16)) = v;
  }
}

// ---------------------------------------------------------------------------
// Kernel 2: erg via bf16 MFMA. 512 thr = 8 waves, 64 KiB LDS (half of WeT
// staged at a time), 2 blocks/CU, 128 rows/block, grid = 512.
// A (enc fp32) streamed from global per lane, software-pipelined one chunk
// ahead; B from LDS (pre-swizzled, conflict-balanced); MFMA accumulate.
// ---------------------------------------------------------------------------
__global__ __launch_bounds__(512, 4) void erg_mfma_kernel(
    const float* __restrict__ enc, const char* __restrict__ WeT,
    const float* __restrict__ dec_ws, const float* __restrict__ ww,
    const float* __restrict__ wb, float* __restrict__ erg_ws) {
  __shared__ __align__(16) char smem[65536];
  const int tid = threadIdx.x;
  const int lane = tid & 63;
  const int m = lane & 15;   // A-row / D-col lane index
  const int g = lane >> 4;   // k-subgroup 0..3
  const int row0 = blockIdx.x * 128 + (tid >> 6) * 16;  // wave's 16 rows
  const int b = row0 >> 11;                             // T = 2048 rows per b

  // Stage half 0 of WeT (chunks 0..3, 64 KiB): tid covers 8 x 16B linearly.
#pragma unroll
  for (int j = 0; j < 8; ++j)
    __builtin_amdgcn_global_load_lds(
        (const __attribute__((address_space(1))) void*)(WeT + j * 8192 + tid * 16),
        (__attribute__((address_space(3))) void*)(&smem[j * 8192 + tid * 16]),
        16, 0, 0);

  // acc init with dec (b_enc folded in): D col = n*16+m; 4 row-regs identical
  f32x4 acc[8];
#pragma unroll
  for (int n = 0; n < 8; ++n) {
    const float d = dec_ws[b * H + n * 16 + m];
    acc[n] = (f32x4){d, d, d, d};
  }

  // lane's A pointer: row (row0+m), k-offset g*8
  const float* arow = enc + (size_t)(row0 + m) * E + g * 8;

  // preload A for chunk 0
  float4 a0 = *(const float4*)(arow);
  float4 a1 = *(const float4*)(arow + 4);
  float4 a2 = *(const float4*)(arow + 32);
  float4 a3 = *(const float4*)(arow + 36);

  asm volatile("s_waitcnt vmcnt(0)" ::: "memory");
  __syncthreads();

#pragma unroll
  for (int c = 0; c < 8; ++c) {
    float4 n0, n1, n2, n3;
    if (c < 7) {  // software-pipelined next-chunk A loads
      const float* ak = arow + (c + 1) * 64;
      n0 = *(const float4*)(ak);
      n1 = *(const float4*)(ak + 4);
      n2 = *(const float4*)(ak + 32);
      n3 = *(const float4*)(ak + 36);
    }
    bf16x8 af0, af1;
    af0[0] = f2b(a0.x); af0[1] = f2b(a0.y); af0[2] = f2b(a0.z); af0[3] = f2b(a0.w);
    af0[4] = f2b(a1.x); af0[5] = f2b(a1.y); af0[6] = f2b(a1.z); af0[7] = f2b(a1.w);
    af1[0] = f2b(a2.x); af1[1] = f2b(a2.y); af1[2] = f2b(a2.z); af1[3] = f2b(a2.w);
    af1[4] = f2b(a3.x); af1[5] = f2b(a3.y); af1[6] = f2b(a3.z); af1[7] = f2b(a3.w);

    const int lc = c & 3;  // chunk slot within staged half
#pragma unroll
    for (int kk = 0; kk < 2; ++kk) {
      const int slot = (((kk * 4) + g) ^ (m & 7)) * 16;
      const bf16x8 af = kk ? af1 : af0;
#pragma unroll
      for (int n = 0; n < 8; ++n) {
        const bf16x8 bf =
            *(const bf16x8*)(&smem[lc * 16384 + (n * 16 + m) * 128 + slot]);
        acc[n] = __builtin_amdgcn_mfma_f32_16x16x32_bf16(af, bf, acc[n], 0, 0, 0);
      }
    }
    a0 = n0; a1 = n1; a2 = n2; a3 = n3;

    if (c == 3) {  // restage: half 1 (chunks 4..7)
      __syncthreads();  // all waves done reading half 0
#pragma unroll
      for (int j = 0; j < 8; ++j)
        __builtin_amdgcn_global_load_lds(
            (const __attribute__((address_space(1))) void*)(WeT + 65536 + j * 8192 + tid * 16),
            (__attribute__((address_space(3))) void*)(&smem[j * 8192 + tid * 16]),
            16, 0, 0);
      asm volatile("s_waitcnt vmcnt(0)" ::: "memory");
      __syncthreads();
    }
  }

  // Epilogue: erg[row] = wb + sum_h ww[h]*tanh(acc). D: row=g*4+j, col=n*16+m.
  const float wbv = wb[0];
  float wwreg[8];
#pragma unroll
  for (int n = 0; n < 8; ++n) wwreg[n] = ww[n * 16 + m];
#pragma unroll
  for (int j = 0; j < 4; ++j) {
    float gsum = 0.0f;
#pragma unroll
    for (int n = 0; n < 8; ++n) {
      const float x = acc[n][j];
      const float th = 1.0f - 2.0f / (__expf(2.0f * x) + 1.0f);
      gsum = fmaf(wwreg[n], th, gsum);
    }
#pragma unroll
    for (int off = 1; off < 16; off <<= 1) gsum += __shfl_xor(gsum, off, 64);
    if (m == 0) erg_ws[row0 + g * 4 + j] = gsum + wbv;
  }
}

// ---------------------------------------------------------------------------
// Kernel 3 (fused, WIDE): softmax + context. Grid (32 chunks x B), 128 thr.
// Each block redundantly computes b's softmax scalars (max, 1/Z) from the
// 8 KB erg row (L2-hit), then streams its 64-row enc slice and atomicAdds
// its 512 distinct ctx columns (one atomic per column per block).
// Block ch==0 additionally writes the weights output row.
// ---------------------------------------------------------------------------
__global__ __launch_bounds__(128) void softctx_kernel(
    const float* __restrict__ enc, const float* __restrict__ erg_ws,
    const int* __restrict__ src_lens, float* __restrict__ w_out,
    float* __restrict__ ctx) {
  const int b = blockIdx.y;
  const int ch = blockIdx.x;  // 0..31, 64 t-rows each
  const int tid = threadIdx.x;
  const int lane = tid & 63, w = tid >> 6;
  const int n = src_lens[b];

  __shared__ float sred[2];
  __shared__ float sscal[2];
  __shared__ float sw[64];

  // ---- softmax scalars (redundant per block) ----
  float v[16];
  float mx = -1e30f;
#pragma unroll
  for (int i = 0; i < 16; ++i) {
    const int t = tid + i * 128;
    const float x = erg_ws[b * T + t];
    v[i] = (t < n) ? x : -1e30f;
    mx = fmaxf(mx, v[i]);
  }
#pragma unroll
  for (int off = 32; off > 0; off >>= 1) mx = fmaxf(mx, __shfl_xor(mx, off, 64));
  if (lane == 0) sred[w] = mx;
  __syncthreads();
  mx = fmaxf(sred[0], sred[1]);
  __syncthreads();

  float s = 0.0f;
#pragma unroll
  for (int i = 0; i < 16; ++i) {
    v[i] = (v[i] > -1e29f) ? __expf(v[i] - mx) : 0.0f;
    s += v[i];
  }
#pragma unroll
  for (int off = 32; off > 0; off >>= 1) s += __shfl_xor(s, off, 64);
  if (lane == 0) sred[w] = s;
  __syncthreads();
  if (tid == 0) sscal[0] = 1.0f / (sred[0] + sred[1]);
  __syncthreads();
  const float inv = sscal[0];

  // weights output (block ch==0 only; v[] holds exp values)
  if (ch == 0) {
#pragma unroll
    for (int i = 0; i < 16; ++i) w_out[b * T + tid + i * 128] = v[i] * inv;
  }

  // this block's 64 row-weights into LDS
  if (tid < 64) {
    const int t = ch * 64 + tid;
    const float x = erg_ws[b * T + t];
    sw[tid] = (t < n) ? __expf(x - mx) * inv : 0.0f;
  }
  __syncthreads();

  // ---- context: 64 rows x E, thread owns float4 column tid ----
  const float4* ep = (const float4*)(enc + ((size_t)b * T + ch * 64) * E) + tid;
  float4 acc = {0.0f, 0.0f, 0.0f, 0.0f};
#pragma unroll 8
  for (int t = 0; t < 64; ++t) {
    const float4 e = ep[(size_t)t * (E / 4)];
    const float wv = sw[t];
    acc.x = fmaf(e.x, wv, acc.x);
    acc.y = fmaf(e.y, wv, acc.y);
    acc.z = fmaf(e.z, wv, acc.z);
    acc.w = fmaf(e.w, wv, acc.w);
  }
  float* c = ctx + b * E + tid * 4;
  atomicAdd(c + 0, acc.x);
  atomicAdd(c + 1, acc.y);
  atomicAdd(c + 2, acc.z);
  atomicAdd(c + 3, acc.w);
}

// ---------------------------------------------------------------------------
extern "C" void kernel_launch(void* const* d_in, const int* in_sizes, int n_in,
                              void* d_out, int out_size, void* d_ws,
                              size_t ws_size, hipStream_t stream) {
  const float* enc = (const float*)d_in[0];   // [B,T,E]
  const int* src_lens = (const int*)d_in[1];  // [B]
  const float* ds = (const float*)d_in[2];    // [B,D]
  // d_in[3] = mask (bool) -- recomputed from src_lens
  const float* We = (const float*)d_in[4];    // [E,H]
  const float* be = (const float*)d_in[5];    // [H]
  const float* Wd = (const float*)d_in[6];    // [D,H]
  const float* ww = (const float*)d_in[7];    // [H,1]
  const float* wb = (const float*)d_in[8];    // [1]

  float* ctx_out = (float*)d_out;             // [B,E]
  float* w_out = (float*)d_out + B * E;       // [B,T]

  float* ws = (float*)d_ws;
  float* dec_ws = ws;                          // 4096 f
  float* erg_ws = ws + B * H;                  // 65536 f
  char* WeT = (char*)(ws + B * H + B * T);     // 128 KiB (bf16, pre-swizzled)

  prep_kernel<<<48, 512, 0, stream>>>(ds, Wd, be, We, dec_ws, WeT, ctx_out);
  erg_mfma_kernel<<<(B * T) / 128, 512, 0, stream>>>(enc, WeT, dec_ws, ww, wb, erg_ws);
  softctx_kernel<<<dim3(32, B), 128, 0, stream>>>(enc, erg_ws, src_lens, w_out, ctx_out);
}